// Round 10
// baseline (28.681 us; speedup 1.0000x reference)
//
#include <hip/hip_runtime.h>
#include <math.h>

// Problem: x[B=32][N=2048][K=8], W[N][C=32][J=16][K=8], R[N][C]
// out[b][c][j] = squash_j( sum_n softmax_n(R)[n,c] * sum_k W[n,c,j,k]*x[b,n,k] )

#define NN 2048
#define CC 32

__device__ __forceinline__ void g2l16(const float* g, float* l) {
  __builtin_amdgcn_global_load_lds((const __attribute__((address_space(1))) void*)g,
                                   (__attribute__((address_space(3))) void*)l, 16, 0, 0);
}

// ---------- Kernel 0: I[c] = 1 / sum_n exp(R[n][c])  (passed every round) ----------
__global__ void caps_stats(const float* __restrict__ R, float* __restrict__ I) {
  const int c = blockIdx.x;   // 0..31
  const int t = threadIdx.x;  // 0..255
  __shared__ float red[256];
  float s = 0.f;
#pragma unroll
  for (int i = 0; i < 8; ++i) s += expf(R[(size_t)(t + i * 256) * CC + c]);
  red[t] = s;
  __syncthreads();
  for (int h = 128; h >= 1; h >>= 1) {
    if (t < h) red[t] += red[t + h];
    __syncthreads();
  }
  if (t == 0) I[c] = 1.0f / red[0];
}

// ---------- Kernel 1: c-octet barrier-free pipelined contraction ----------
// grid 256: chunk = bid&63 (32 n), cg = bid>>6 (8 c). XCD = bid%8 = chunk%8 -> the 4
// cg-blocks of a chunk share an XCD (x slice L2-resident). block 512 = 8 waves,
// 128KB LDS -> 1 block/CU. Rationale (R9 analysis): main was LDS-INSTRUCTION-bound
// (~1536 ds_read_b128/CU); c-octet amortizes broadcast x-reads over 2x FMAs -> 1024.
// Wave-private staging: wave ws owns n = n0+ws*4..+4.
//   W: per n 256 granules (4 g2l16) into 3-buf ring; slot S holds source granule
//      g = S ^ ((S>>3)&3)   [involution; read side: slot = (ci*32+j*2+kh) ^ (j>>2),
//      2-way bank spread = free]
//   x: per n 64 granules (1 g2l16; per-lane src does k<->b transpose);
//      slot S = G ^ ((G>>4)<<1), G = b*2+kq  [R7-verified, conflict-free]
// Sync discipline (R7's, passed twice): explicit counted vmcnt before EVERY compute
// (never rely on barrier-implied vmem drain - R9's race), sched_barrier(0) after
// every wait (rule #18), lgkmcnt(0) WAR guard before the ring-wrap stage.
// NO occupancy attributes: measured (R4/R6) they clamp VGPR to 64 -> ~60MB spill.
__global__ void __launch_bounds__(512) caps_main(const float* __restrict__ x,
                                                 const float* __restrict__ W,
                                                 const float* __restrict__ R,
                                                 const float* __restrict__ I,
                                                 float* __restrict__ P) {
  const int bid = blockIdx.x;
  const int cg = bid >> 6;      // c-octet 0..3
  const int chunk = bid & 63;
  const int n0 = chunk * 32;
  const int tid = threadIdx.x;
  const int ws = tid >> 6;
  const int lane = tid & 63;
  const int j = lane & 15;
  const int bo = lane >> 4;

  extern __shared__ float smem[];   // 8 waves x 4096 floats = 128 KB
  float* wREG = smem + ws * 4096;
  float* wW = wREG;                 // 3 bufs x 1024 floats (one n-slab each)
  float* wX = wREG + 3072;          // 4 n x 256 floats
  const int nw = n0 + ws * 4;

  // ---- register loads FIRST (retire ahead of the g2l16 queue; keeps vmcnt
  //      accounting exact: 10 reg-load instrs are the oldest entries) ----
  float4 iv0 = *(const float4*)(I + cg * 8);
  float4 iv1 = *(const float4*)(I + cg * 8 + 4);
  float4 rq0[4], rq1[4];
#pragma unroll
  for (int nl = 0; nl < 4; ++nl) {
    rq0[nl] = *(const float4*)(R + (size_t)(nw + nl) * CC + cg * 8);
    rq1[nl] = *(const float4*)(R + (size_t)(nw + nl) * CC + cg * 8 + 4);
  }

  auto stageW = [&](int nl, int buf) {
#pragma unroll
    for (int i = 0; i < 4; ++i) {
      int S = i * 64 + lane;
      int g = S ^ ((S >> 3) & 3);   // involution: bits3-4 (j>>2) -> bits0-1
      g2l16(W + (size_t)(nw + nl) * 4096 + cg * 1024 + g * 4,
            wW + buf * 1024 + i * 256);
    }
  };

  // ---- issue: W n0 -> buf0, x all 4 n, W n1 -> buf1  [queue: 10reg+4+4+4] ----
  stageW(0, 0);
  {
    int g2 = lane ^ ((lane >> 4) << 1);   // slot 'lane' holds granule g2
    int b = g2 >> 1, kq = g2 & 1;
    const float* xs = x + (size_t)b * (NN * 8) + kq * 4;
#pragma unroll
    for (int nl = 0; nl < 4; ++nl)
      g2l16(xs + (size_t)(nw + nl) * 8, wX + nl * 256);
  }
  stageW(1, 1);

  // routing weights (compiler auto-waits for rq/iv values; only strengthens)
  float rv[4][8];
#pragma unroll
  for (int nl = 0; nl < 4; ++nl) {
    rv[nl][0] = expf(rq0[nl].x) * iv0.x;
    rv[nl][1] = expf(rq0[nl].y) * iv0.y;
    rv[nl][2] = expf(rq0[nl].z) * iv0.z;
    rv[nl][3] = expf(rq0[nl].w) * iv0.w;
    rv[nl][4] = expf(rq1[nl].x) * iv1.x;
    rv[nl][5] = expf(rq1[nl].y) * iv1.y;
    rv[nl][6] = expf(rq1[nl].z) * iv1.z;
    rv[nl][7] = expf(rq1[nl].w) * iv1.w;
  }

  float acc[8][8];
#pragma unroll
  for (int a = 0; a < 8; ++a)
#pragma unroll
    for (int b = 0; b < 8; ++b) acc[a][b] = 0.f;

  auto compute = [&](int nl, int buf) {
    const float* Wn = wW + buf * 1024;
    const float* Xn = wX + nl * 256;
#pragma unroll
    for (int kh = 0; kh < 2; ++kh) {
      float4 xv[8];
#pragma unroll
      for (int bi = 0; bi < 8; ++bi) {
        int G = (bo * 8 + bi) * 2 + kh;
        int S = G ^ ((G >> 4) << 1);
        xv[bi] = *(const float4*)(Xn + S * 4);
      }
#pragma unroll
      for (int ci = 0; ci < 8; ++ci) {
        int slot = (ci * 32 + j * 2 + kh) ^ (j >> 2);
        float4 wf = *(const float4*)(Wn + slot * 4);
        float rvv = rv[nl][ci];
        float w0 = wf.x * rvv, w1 = wf.y * rvv, w2 = wf.z * rvv, w3 = wf.w * rvv;
#pragma unroll
        for (int bi = 0; bi < 8; ++bi) {
          float a = acc[ci][bi];
          a = fmaf(w0, xv[bi].x, a);
          a = fmaf(w1, xv[bi].y, a);
          a = fmaf(w2, xv[bi].z, a);
          a = fmaf(w3, xv[bi].w, a);
          acc[ci][bi] = a;
        }
      }
    }
  };

  // ---- pipeline: explicit counted wait before EVERY compute; 0 barriers ----
  stageW(2, 2);                                       // queue: 10reg,W0,x,W1,W2 = 26
  asm volatile("s_waitcnt vmcnt(8)" ::: "memory");    // leaves W1+W2 -> W0,x landed
  __builtin_amdgcn_sched_barrier(0);
  compute(0, 0);
  asm volatile("s_waitcnt lgkmcnt(0)" ::: "memory");  // compute0 LDS reads retired
  __builtin_amdgcn_sched_barrier(0);
  stageW(3, 0);                                       // ring wrap onto buf0
  asm volatile("s_waitcnt vmcnt(8)" ::: "memory");    // leaves W2+W3 -> W1 landed
  __builtin_amdgcn_sched_barrier(0);
  compute(1, 1);
  asm volatile("s_waitcnt vmcnt(4)" ::: "memory");    // leaves W3 -> W2 landed
  __builtin_amdgcn_sched_barrier(0);
  compute(2, 2);
  asm volatile("s_waitcnt vmcnt(0)" ::: "memory");    // W3 landed
  __builtin_amdgcn_sched_barrier(0);
  compute(3, 0);

  // ---- epilogue: dump wave-own region (in-wave DS order safe), 1 barrier,
  //      per-wave c-cell sums, coalesced P write ----
#pragma unroll
  for (int ci = 0; ci < 8; ++ci)
#pragma unroll
    for (int bi = 0; bi < 8; ++bi)
      wREG[(ci * 8 + bi) * 64 + lane] = acc[ci][bi];   // consecutive lanes: free
  __syncthreads();
  {
    // wave ws sums c-cells ws*8..+8 (lane-consecutive reads: conflict-free)
    float ssum[8];
#pragma unroll
    for (int i = 0; i < 8; ++i) ssum[i] = 0.f;
#pragma unroll
    for (int w = 0; w < 8; ++w)
#pragma unroll
      for (int i = 0; i < 8; ++i)
        ssum[i] += smem[(size_t)w * 4096 + (ws * 8 + i) * 64 + lane];
#pragma unroll
    for (int i = 0; i < 8; ++i)
      P[(size_t)bid * 4096 + (ws * 8 + i) * 64 + lane] = ssum[i];
  }
}

// ---------- Kernel 2: cross-chunk reduce + squash ----------
// P[bid = cg*64 + ch][cell = (ci*8+bi)*64 + bo*16 + j], cg 2 bits / ci 3 bits now.
__global__ void caps_reduce(const float* __restrict__ P, float* __restrict__ out) {
  const int g = blockIdx.x * 256 + threadIdx.x;  // b*512 + c*16 + j
  const int j = g & 15;
  const int c = (g >> 4) & 31;
  const int b = g >> 9;
  const int bo = b >> 3, bi = b & 7;
  const int cg = c >> 3, ci = c & 7;
  const int idx = (ci * 8 + bi) * 64 + (bo * 16 + j);
  const float* Pq = P + (size_t)cg * 64 * 4096 + idx;

  float s = 0.f;
#pragma unroll 16
  for (int ch = 0; ch < 64; ++ch) {
    s += Pq[(size_t)ch * 4096];
  }
  float sq = s * s;
  sq += __shfl_xor(sq, 8, 16);
  sq += __shfl_xor(sq, 4, 16);
  sq += __shfl_xor(sq, 2, 16);
  sq += __shfl_xor(sq, 1, 16);
  float ss = sq + 1e-7f;
  float scale = sqrtf(ss) / (1.0f + ss);
  out[g] = scale * s;
}

extern "C" void kernel_launch(void* const* d_in, const int* in_sizes, int n_in,
                              void* d_out, int out_size, void* d_ws, size_t ws_size,
                              hipStream_t stream) {
  const float* x = (const float*)d_in[0];   // 32*2048*8
  const float* W = (const float*)d_in[1];   // 2048*32*16*8
  const float* R = (const float*)d_in[2];   // 2048*32
  float* out = (float*)d_out;               // 32*32*16

  float* I = (float*)d_ws;                  // 32 floats (pad to 64)
  float* P = (float*)d_ws + 64;             // 256*4096 floats (4 MB)

  hipFuncSetAttribute((const void*)caps_main,
                      hipFuncAttributeMaxDynamicSharedMemorySize, 131072);

  caps_stats<<<32, 256, 0, stream>>>(R, I);
  caps_main<<<256, 512, 131072, stream>>>(x, W, R, I, P);
  caps_reduce<<<64, 256, 0, stream>>>(P, out);
}